// Round 3
// baseline (9990.635 us; speedup 1.0000x reference)
//
#include <hip/hip_runtime.h>

// Problem constants
#define BATCH 256
#define TT    64
#define HH    256
#define DIN   2
#define DD    8

#define BW    2
#define NTHR  512
#define NBLK  (2 * (BATCH / BW))   // 256 WGs -> 1 per CU

typedef __attribute__((ext_vector_type(8))) short bfrag;   // 8 bf16 (MFMA A/B operand)
typedef __attribute__((ext_vector_type(4))) float f4;      // MFMA C/D

// ---------- helpers ----------
__device__ __forceinline__ float rcpf(float x) { return __builtin_amdgcn_rcpf(x); }
__device__ __forceinline__ float sigf(float x) { return rcpf(1.0f + __expf(-x)); }
__device__ __forceinline__ float tanh_fast(float x) {
  const float ax = fabsf(x);
  const float t  = __expf(-2.0f * ax);
  const float r  = (1.0f - t) * rcpf(1.0f + t);
  return copysignf(r, x);
}
__device__ __forceinline__ unsigned short f2bf(float f) {  // RNE fp32 -> bf16
  union { float f; unsigned int u; } v; v.f = f;
  unsigned int r = (v.u + 0x7fffu + ((v.u >> 16) & 1u)) >> 16;
  return (unsigned short)r;
}
__device__ __forceinline__ float bf2f(unsigned short u) {
  union { unsigned int u; float f; } v; v.u = ((unsigned int)u) << 16;
  return v.f;
}
__device__ __forceinline__ float bf_lo(unsigned int u) {
  union { unsigned int u; float f; } v; v.u = u << 16; return v.f;
}
__device__ __forceinline__ float bf_hi(unsigned int u) {
  union { unsigned int u; float f; } v; v.u = u & 0xffff0000u; return v.f;
}
__device__ __forceinline__ bfrag zero_frag() {
  bfrag r;
#pragma unroll
  for (int x = 0; x < 8; x++) r[x] = 0;
  return r;
}
__device__ __forceinline__ bfrag pack8(const float* p) {   // 8 consecutive fp32 -> bf16 frag
  bfrag r;
#pragma unroll
  for (int x = 0; x < 8; x++) r[x] = (short)f2bf(p[x]);
  return r;
}

// ---------- weight fragment layout ----------
// Per GEMM region: frag index f = (t*KC + c)*64 + lane; ushort e = f*8 + j
// holds B[k][n] with n = t*16 + (lane&15), k = c*32 + (lane>>4)*8 + j.
#define W1_ELEMS   196608   // K=256 (KC=8),  N=768 (48 tiles)
#define W2_ELEMS   196608
#define STACK_W    (3 * 196608)          // W1, W2I, W2H
#define B3_OFF     (2 * STACK_W)         // K=256, N=512 (32 tiles): 131072
#define B4_OFF     (B3_OFF + 131072)     // K=512 (KC=16), N=256 (16 tiles): 131072
#define WF_TOTAL   (B4_OFF + 131072)     // 1,441,792 ushorts

__global__ __launch_bounds__(256) void prep_weights(
    const float* __restrict__ g1_Whh0, const float* __restrict__ g1_Wih1, const float* __restrict__ g1_Whh1,
    const float* __restrict__ g2_Whh0, const float* __restrict__ g2_Wih1, const float* __restrict__ g2_Whh1,
    const float* __restrict__ attn_W, const float* __restrict__ fc_W,
    unsigned short* __restrict__ wf) {
  const int id = blockIdx.x * 256 + threadIdx.x;
  if (id >= WF_TOTAL) return;
  float src;
  if (id < 2 * STACK_W) {                     // GRU weights, K=256
    const int s = id / STACK_W;
    const int r = id % STACK_W;
    const int m = r / W1_ELEMS;               // 0=Whh0, 1=Wih1, 2=Whh1
    const int e = r % W1_ELEMS;
    const int j = e & 7, lane = (e >> 3) & 63, c = (e >> 9) & 7, t = e >> 12;
    const int n = t * 16 + (lane & 15);
    const int k = c * 32 + ((lane >> 4) << 3) + j;
    const float* W = (m == 0) ? (s ? g2_Whh0 : g1_Whh0)
                   : (m == 1) ? (s ? g2_Wih1 : g1_Wih1)
                              : (s ? g2_Whh1 : g1_Whh1);
    src = W[n * 256 + k];
  } else if (id < B4_OFF) {                   // attn (B3), K=256, N=512
    const int e = id - B3_OFF;
    const int j = e & 7, lane = (e >> 3) & 63, c = (e >> 9) & 7, t = e >> 12;
    const int n = t * 16 + (lane & 15);
    const int k = c * 32 + ((lane >> 4) << 3) + j;
    src = (n < 256) ? attn_W[n * 512 + k] : attn_W[(n - 256) * 512 + 256 + k];
  } else {                                    // fc (B4), K=512, N=256
    const int e = id - B4_OFF;
    const int j = e & 7, lane = (e >> 3) & 63, c = (e >> 9) & 15, t = e >> 13;
    const int n = t * 16 + (lane & 15);
    const int k = c * 32 + ((lane >> 4) << 3) + j;
    src = fc_W[n * 512 + k];
  }
  wf[id] = f2bf(src);
}

// ---------- persistent recurrence kernel ----------
struct __align__(16) SMEM {
  float h [2][BW][HH];       // attended carry (fp32 -- precision-critical leak path)
  float hn[2][BW][HH];       // fresh GRU hidden
  float S1[BW][3 * HH];      // gh0 / gi1
  float S2[BW][3 * HH];      // gh1
  float es[BW][2][264];      // s-projection (padded)
  float cac[2][BW][HH];      // attention context
  float lp[BW][TT][2][2];    // logits (b,j,l,o)
  float aw[BW][TT][2][2];    // softmax weights
  float vw[2 * HH];
  float pw[8];
  float xsh[BW][DIN];
};

__global__ __launch_bounds__(NTHR, 2) void gru_attn_persistent(
    const float* __restrict__ received,
    const float* __restrict__ g1_Wih0, const float* __restrict__ g1_bih0, const float* __restrict__ g1_bhh0,
    const float* __restrict__ g1_bih1, const float* __restrict__ g1_bhh1,
    const float* __restrict__ g2_Wih0, const float* __restrict__ g2_bih0, const float* __restrict__ g2_bhh0,
    const float* __restrict__ g2_bih1, const float* __restrict__ g2_bhh1,
    const float* __restrict__ fc_b, const float* __restrict__ v_W, const float* __restrict__ out_W,
    const unsigned short* __restrict__ wf,
    unsigned short* __restrict__ ws_buf, unsigned short* __restrict__ ws_eh,
    float* __restrict__ ws_p) {
  const int tid  = threadIdx.x;
  const int lane = tid & 63;
  const int wave = tid >> 6;
  const int s    = blockIdx.x & 1;    // stack parity -> XCD parity
  const int bb   = blockIdx.x >> 1;
  const int b0   = bb * BW;

  const float* Wih0 = s ? g2_Wih0 : g1_Wih0;
  const float* bih0 = s ? g2_bih0 : g1_bih0;
  const float* bhh0 = s ? g2_bhh0 : g1_bhh0;
  const float* bih1 = s ? g2_bih1 : g1_bih1;
  const float* bhh1 = s ? g2_bhh1 : g1_bhh1;

  const unsigned short* wsW1  = wf + (size_t)s * STACK_W;
  const unsigned short* wsW2I = wsW1 + W1_ELEMS;
  const unsigned short* wsW2H = wsW1 + 2 * W1_ELEMS;
  const unsigned short* wsB3  = wf + B3_OFF;
  const unsigned short* wsB4  = wf + B4_OFF;

  unsigned short* buf = ws_buf + (size_t)s * BATCH * TT * 2 * HH;
  unsigned short* ehb = ws_eh  + (size_t)s * BATCH * TT * 2 * HH;
  float* pp = ws_p + (size_t)s * BATCH * TT;
  const float* outw = out_W + s * HH;

  __shared__ SMEM sm;
  for (int idx = tid; idx < 2 * BW * HH; idx += NTHR) (&sm.h[0][0][0])[idx] = 0.0f;
  sm.vw[tid] = v_W[tid];
  __syncthreads();

  const int m = lane & 15;    // MFMA A-row / C-col index
  const int q = lane >> 4;    // k-quad
  const int k = tid & (HH - 1);
  const int half = tid >> 8;  // b for gate phases

#pragma unroll 1
  for (int i = 0; i < TT; ++i) {
    // ===== ph1: x load + G1 (gh0 = h0 @ Whh0^T) via MFMA -> S1 =====
    if (tid < BW * DIN) {
      const int b = tid >> 1, c = tid & 1;
      sm.xsh[b][c] = received[(size_t)(b0 + b) * TT * DIN + i * DIN + c];
    }
    {
      bfrag a[8];
#pragma unroll
      for (int c = 0; c < 8; c++)
        a[c] = (m < BW) ? pack8(&sm.h[0][m][c * 32 + q * 8]) : zero_frag();
#pragma unroll
      for (int tt = 0; tt < 6; tt++) {
        const int t = wave * 6 + tt;
        const bfrag* bp = ((const bfrag*)wsW1) + (size_t)(t * 8) * 64 + lane;
        f4 acc = {0.f, 0.f, 0.f, 0.f};
#pragma unroll
        for (int c = 0; c < 8; c++)
          acc = __builtin_amdgcn_mfma_f32_16x16x32_bf16(a[c], bp[c * 64], acc, 0, 0, 0);
        if (lane < 16) {
          sm.S1[0][t * 16 + lane] = acc[0];
          sm.S1[1][t * 16 + lane] = acc[1];
        }
      }
    }
    __syncthreads();

    // ===== ph2: layer-0 gates -> hn0 (fp32) =====
    {
      const int b = half;
      const float x0 = sm.xsh[b][0], x1 = sm.xsh[b][1];
      const float2 wr = ((const float2*)Wih0)[k];
      const float2 wz = ((const float2*)Wih0)[k + HH];
      const float2 wn = ((const float2*)Wih0)[k + 2 * HH];
      const float r = sigf(x0 * wr.x + x1 * wr.y + bih0[k] + sm.S1[b][k] + bhh0[k]);
      const float z = sigf(x0 * wz.x + x1 * wz.y + bih0[k + HH] + sm.S1[b][k + HH] + bhh0[k + HH]);
      const float n = tanh_fast(x0 * wn.x + x1 * wn.y + bih0[k + 2 * HH] +
                                r * (sm.S1[b][k + 2 * HH] + bhh0[k + 2 * HH]));
      sm.hn[0][b][k] = (1.0f - z) * n + z * sm.h[0][b][k];
    }
    __syncthreads();

    // ===== ph3: G2 = gi1 (hn0 @ Wih1^T -> S1) and gh1 (h1 @ Whh1^T -> S2) =====
    {
      bfrag ai[8], ah[8];
#pragma unroll
      for (int c = 0; c < 8; c++) {
        ai[c] = (m < BW) ? pack8(&sm.hn[0][m][c * 32 + q * 8]) : zero_frag();
        ah[c] = (m < BW) ? pack8(&sm.h[1][m][c * 32 + q * 8]) : zero_frag();
      }
#pragma unroll
      for (int tt = 0; tt < 6; tt++) {
        const int t = wave * 6 + tt;
        const bfrag* bpi = ((const bfrag*)wsW2I) + (size_t)(t * 8) * 64 + lane;
        const bfrag* bph = ((const bfrag*)wsW2H) + (size_t)(t * 8) * 64 + lane;
        f4 ai_acc = {0.f, 0.f, 0.f, 0.f};
        f4 ah_acc = {0.f, 0.f, 0.f, 0.f};
#pragma unroll
        for (int c = 0; c < 8; c++) {
          ai_acc = __builtin_amdgcn_mfma_f32_16x16x32_bf16(ai[c], bpi[c * 64], ai_acc, 0, 0, 0);
          ah_acc = __builtin_amdgcn_mfma_f32_16x16x32_bf16(ah[c], bph[c * 64], ah_acc, 0, 0, 0);
        }
        if (lane < 16) {
          sm.S1[0][t * 16 + lane] = ai_acc[0];
          sm.S1[1][t * 16 + lane] = ai_acc[1];
          sm.S2[0][t * 16 + lane] = ah_acc[0];
          sm.S2[1][t * 16 + lane] = ah_acc[1];
        }
      }
    }
    __syncthreads();

    // ===== ph4: layer-1 gates -> hn1; store buf (bf16); out_W wave partial =====
    {
      const int b = half;
      const float r = sigf(sm.S1[b][k] + bih1[k] + sm.S2[b][k] + bhh1[k]);
      const float z = sigf(sm.S1[b][k + HH] + bih1[k + HH] + sm.S2[b][k + HH] + bhh1[k + HH]);
      const float n = tanh_fast(sm.S1[b][k + 2 * HH] + bih1[k + 2 * HH] +
                                r * (sm.S2[b][k + 2 * HH] + bhh1[k + 2 * HH]));
      const float hn1 = (1.0f - z) * n + z * sm.h[1][b][k];
      sm.hn[1][b][k] = hn1;
      const float hn0 = sm.hn[0][b][k];
      const size_t base = ((size_t)(b0 + b) * TT * 2 + i * 2) * HH + k;
      buf[base]      = f2bf(hn0);
      buf[base + HH] = f2bf(hn1);
      float pv = hn1 * outw[k];
#pragma unroll
      for (int d = 1; d < 64; d <<= 1) pv += __shfl_xor(pv, d, 64);
      if (lane == 0) sm.pw[wave] = pv;
    }
    __syncthreads();

    // ===== ph5: G3 = hn(l,b) @ [attnW_s^T | attnW_h^T] -> es (LDS) / ehb (global); pp =====
    if (tid < BW)
      pp[(size_t)(b0 + tid) * TT + i] = sm.pw[4 * tid] + sm.pw[4 * tid + 1] +
                                        sm.pw[4 * tid + 2] + sm.pw[4 * tid + 3];
    {
      bfrag a[8];
#pragma unroll
      for (int c = 0; c < 8; c++)
        a[c] = (m < 4) ? pack8(&sm.hn[m >> 1][m & 1][c * 32 + q * 8]) : zero_frag();
#pragma unroll
      for (int tt = 0; tt < 4; tt++) {
        const int t = wave * 4 + tt;
        const bfrag* bp = ((const bfrag*)wsB3) + (size_t)(t * 8) * 64 + lane;
        f4 acc = {0.f, 0.f, 0.f, 0.f};
#pragma unroll
        for (int c = 0; c < 8; c++)
          acc = __builtin_amdgcn_mfma_f32_16x16x32_bf16(a[c], bp[c * 64], acc, 0, 0, 0);
        if (lane < 16) {
          const int n = t * 16 + lane;
#pragma unroll
          for (int r = 0; r < 4; r++) {
            const int l = r >> 1, b = r & 1;
            if (n < 256) sm.es[b][l][n] = acc[r];
            else ehb[((size_t)(b0 + b) * TT * 2 + i * 2 + l) * HH + (n - 256)] = f2bf(acc[r]);
          }
        }
      }
    }
    __syncthreads();

    // ===== ph6: energy tanh + logits (8 lanes per (b,l,j) row, coalesced 64B/lane) =====
    {
      const int ntask = 32 * (i + 1);
      for (int task = tid; task < ntask; task += NTHR) {
        const int g8 = task & 7;
        const int b  = (task >> 3) & 1;
        const int l  = (task >> 4) & 1;
        const int j  = task >> 5;
        const uint4* ep = (const uint4*)(ehb + ((size_t)(b0 + b) * TT * 2 + j * 2 + l) * HH + g8 * 32);
        const float* esr = &sm.es[b][l][g8 * 32];
        const float* v0  = &sm.vw[g8 * 32];
        const float* v1  = &sm.vw[HH + g8 * 32];
        float l0 = 0.0f, l1 = 0.0f;
#pragma unroll
        for (int qq = 0; qq < 4; qq++) {
          const uint4 u = ep[qq];
          const unsigned int w[4] = {u.x, u.y, u.z, u.w};
#pragma unroll
          for (int r = 0; r < 4; r++) {
            const int g = qq * 8 + r * 2;
            const float e0 = tanh_fast(esr[g] + bf_lo(w[r]));
            const float e1 = tanh_fast(esr[g + 1] + bf_hi(w[r]));
            l0 += e0 * v0[g] + e1 * v0[g + 1];
            l1 += e0 * v1[g] + e1 * v1[g + 1];
          }
        }
#pragma unroll
        for (int d = 1; d < 8; d <<= 1) {
          l0 += __shfl_xor(l0, d, 64);
          l1 += __shfl_xor(l1, d, 64);
        }
        if (g8 == 0) { sm.lp[b][j][l][0] = l0; sm.lp[b][j][l][1] = l1; }
      }
    }
    __syncthreads();

    // ===== ph7: wave-parallel masked softmax (wave per (b,o)) =====
    if (tid < 256) {
      const int ln = tid & 63, wid = tid >> 6;
      const int b = wid >> 1, o = wid & 1;
      const int jl2 = 2 * (i + 1);
      const int jl0 = ln, jl1 = ln + 64;
      float v0 = -1e30f, v1 = -1e30f;
      if (jl0 < jl2) v0 = sm.lp[b][jl0 >> 1][jl0 & 1][o];
      if (jl1 < jl2) v1 = sm.lp[b][jl1 >> 1][jl1 & 1][o];
      float mx = fmaxf(v0, v1);
#pragma unroll
      for (int d = 1; d < 64; d <<= 1) mx = fmaxf(mx, __shfl_xor(mx, d, 64));
      float e0 = (jl0 < jl2) ? __expf(v0 - mx) : 0.0f;
      float e1 = (jl1 < jl2) ? __expf(v1 - mx) : 0.0f;
      float ssum = e0 + e1;
#pragma unroll
      for (int d = 1; d < 64; d <<= 1) ssum += __shfl_xor(ssum, d, 64);
      const float inv = rcpf(ssum);
      if (jl0 < jl2) sm.aw[b][jl0 >> 1][jl0 & 1][o] = e0 * inv;
      if (jl1 < jl2) sm.aw[b][jl1 >> 1][jl1 & 1][o] = e1 * inv;
    }
    __syncthreads();

    // ===== ph8: context (thread = (b,h)) reading bf16 buf =====
    {
      const int b = half, h = k;
      const unsigned short* bp = buf + ((size_t)(b0 + b) * TT * 2) * HH + h;
      float c0 = 0.0f, c1 = 0.0f;
      for (int j = 0; j <= i; j++) {
#pragma unroll
        for (int l = 0; l < 2; l++) {
          const float v = bf2f(bp[(size_t)(j * 2 + l) * HH]);
          c0 += sm.aw[b][j][l][0] * v;
          c1 += sm.aw[b][j][l][1] * v;
        }
      }
      sm.cac[0][b][h] = c0;
      sm.cac[1][b][h] = c1;
    }
    __syncthreads();

    // ===== ph9: G4 = [cac|hn] @ fc_W^T + fc_b -> new carry h =====
    {
      bfrag a[16];
      if (m < 4) {
        const int o = m >> 1, b = m & 1;
#pragma unroll
        for (int c = 0; c < 8; c++) {
          a[c]     = pack8(&sm.cac[o][b][c * 32 + q * 8]);
          a[c + 8] = pack8(&sm.hn[o][b][c * 32 + q * 8]);
        }
      } else {
#pragma unroll
        for (int c = 0; c < 16; c++) a[c] = zero_frag();
      }
#pragma unroll
      for (int tt = 0; tt < 2; tt++) {
        const int t = wave * 2 + tt;
        const bfrag* bp = ((const bfrag*)wsB4) + (size_t)(t * 16) * 64 + lane;
        f4 acc = {0.f, 0.f, 0.f, 0.f};
#pragma unroll
        for (int c = 0; c < 16; c++)
          acc = __builtin_amdgcn_mfma_f32_16x16x32_bf16(a[c], bp[c * 64], acc, 0, 0, 0);
        if (lane < 16) {
          const int n = t * 16 + lane;
          const float bv = fc_b[n];
#pragma unroll
          for (int r = 0; r < 4; r++) sm.h[r >> 1][r & 1][n] = acc[r] + bv;
        }
      }
    }
    __syncthreads();
  }
}

__global__ __launch_bounds__(256) void final_combine(const float* __restrict__ ws_p,
                                                     const float* __restrict__ out_b,
                                                     float* __restrict__ out) {
  const int gidx = blockIdx.x * blockDim.x + threadIdx.x;
  if (gidx >= BATCH * TT) return;
  const int b = gidx >> 6;
  const int t = gidx & 63;
  const int idx = (t >= TT - DD - 1) ? (TT - 1) : (t + DD);
  const float* p1 = ws_p;
  const float* p2 = ws_p + (size_t)BATCH * TT;
  const float v = p1[(size_t)b * TT + t] + p2[(size_t)b * TT + idx] + out_b[0];
  out[gidx] = 1.0f / (1.0f + __expf(-v));
}

extern "C" void kernel_launch(void* const* d_in, const int* in_sizes, int n_in,
                              void* d_out, int out_size, void* d_ws, size_t ws_size,
                              hipStream_t stream) {
  const float* received = (const float*)d_in[0];
  const float* g1_Wih0 = (const float*)d_in[1];
  const float* g1_Whh0 = (const float*)d_in[2];
  const float* g1_bih0 = (const float*)d_in[3];
  const float* g1_bhh0 = (const float*)d_in[4];
  const float* g1_Wih1 = (const float*)d_in[5];
  const float* g1_Whh1 = (const float*)d_in[6];
  const float* g1_bih1 = (const float*)d_in[7];
  const float* g1_bhh1 = (const float*)d_in[8];
  const float* g2_Wih0 = (const float*)d_in[9];
  const float* g2_Whh0 = (const float*)d_in[10];
  const float* g2_bih0 = (const float*)d_in[11];
  const float* g2_bhh0 = (const float*)d_in[12];
  const float* g2_Wih1 = (const float*)d_in[13];
  const float* g2_Whh1 = (const float*)d_in[14];
  const float* g2_bih1 = (const float*)d_in[15];
  const float* g2_bhh1 = (const float*)d_in[16];
  const float* fc_W   = (const float*)d_in[17];
  const float* fc_b   = (const float*)d_in[18];
  const float* attn_W = (const float*)d_in[19];
  const float* v_W    = (const float*)d_in[20];
  const float* out_W  = (const float*)d_in[21];
  const float* out_b  = (const float*)d_in[22];

  // ws layout:
  //   floats : ws_p [2*B*T]                       = 32768 f
  //   ushort : buf  [2*B*T*2*H]                   = 16,777,216
  //   ushort : ehb  [2*B*T*2*H]                   = 16,777,216
  //   ushort : wf   [WF_TOTAL]                    = 1,441,792
  float* ws_p = (float*)d_ws;
  unsigned short* buf = (unsigned short*)(ws_p + 2 * BATCH * TT);
  unsigned short* ehb = buf + (size_t)2 * BATCH * TT * 2 * HH;
  unsigned short* wf  = ehb + (size_t)2 * BATCH * TT * 2 * HH;

  hipLaunchKernelGGL(prep_weights, dim3((WF_TOTAL + 255) / 256), dim3(256), 0, stream,
                     g1_Whh0, g1_Wih1, g1_Whh1, g2_Whh0, g2_Wih1, g2_Whh1,
                     attn_W, fc_W, wf);

  hipLaunchKernelGGL(gru_attn_persistent, dim3(NBLK), dim3(NTHR), 0, stream,
                     received,
                     g1_Wih0, g1_bih0, g1_bhh0, g1_bih1, g1_bhh1,
                     g2_Wih0, g2_bih0, g2_bhh0, g2_bih1, g2_bhh1,
                     fc_b, v_W, out_W, wf, buf, ehb, ws_p);

  hipLaunchKernelGGL(final_combine, dim3((BATCH * TT + 255) / 256), dim3(256), 0, stream,
                     ws_p, out_b, (float*)d_out);
}

// Round 4
// 6185.400 us; speedup vs baseline: 1.6152x; 1.6152x over previous
//
#include <hip/hip_runtime.h>

// Problem constants
#define BATCH 256
#define TT    64
#define HH    256
#define DD    8

// Tiling: 2 stacks * 64 batch-blocks of BW=4 -> 128 WGs, 1024 thr (16 waves)
#define BW    4
#define NTHR  1024
#define NBLK  (2 * (BATCH / BW))

typedef __attribute__((ext_vector_type(8))) short bfrag;   // 8 bf16 (MFMA A/B operand)
typedef __attribute__((ext_vector_type(4))) float f4;      // MFMA C/D
typedef unsigned int uint_t;
typedef __attribute__((ext_vector_type(4))) unsigned int uv4;

// LDS bank-swizzle for the g-indexed rows read with g8-stride-32 in the energy
// phase: swz makes those reads stride-1 across lanes (conflict-free).
#define SWZ(g) ((((g) & 31) << 3) | ((g) >> 5))

__device__ __forceinline__ float rcpf(float x) { return __builtin_amdgcn_rcpf(x); }
__device__ __forceinline__ float sigf(float x) { return rcpf(1.0f + __expf(-x)); }
__device__ __forceinline__ float tanh_fast(float x) {
  const float e = __expf(-2.0f * x);
  return __builtin_fmaf(2.0f, rcpf(1.0f + e), -1.0f);
}
__device__ __forceinline__ unsigned short f2bf(float f) {  // RNE fp32 -> bf16
  union { float f; unsigned int u; } v; v.f = f;
  return (unsigned short)((v.u + 0x7fffu + ((v.u >> 16) & 1u)) >> 16);
}
__device__ __forceinline__ float bf_lo(unsigned int u) {
  union { unsigned int u; float f; } v; v.u = u << 16; return v.f;
}
__device__ __forceinline__ float bf_hi(unsigned int u) {
  union { unsigned int u; float f; } v; v.u = u & 0xffff0000u; return v.f;
}
__device__ __forceinline__ bfrag zero_frag() {
  bfrag r;
#pragma unroll
  for (int x = 0; x < 8; x++) r[x] = 0;
  return r;
}
__device__ __forceinline__ f4 mfma16(bfrag a, bfrag b, f4 c) {
  return __builtin_amdgcn_mfma_f32_16x16x32_bf16(a, b, c, 0, 0, 0);
}

// ---------- weight fragment layout ----------
// GRU regions (K=256): tile t = ntile*3 + gate, so one wave owns the SAME
// 16 output units for all three gates -> gates combine in-register.
// frag f = (t*KC + c)*64 + lane; elem e = f*8 + j holds B[k][n]:
//   n = ntile*16 + (lane&15), k = c*32 + (lane>>4)*8 + j.
#define W1_ELEMS  196608                 // 48 tiles (16 ntiles x 3 gates)
#define STACK_W   (3 * W1_ELEMS)         // Whh0, Wih1, Whh1
#define B3_OFF    (2 * STACK_W)          // attn: K=256, N=512 (32 plain tiles)
#define B4_OFF    (B3_OFF + 131072)      // fc:   K=512 (KC=16), N=256 (16 tiles)
#define WF_TOTAL  (B4_OFF + 131072)

__global__ __launch_bounds__(256) void prep_weights(
    const float* __restrict__ g1_Whh0, const float* __restrict__ g1_Wih1, const float* __restrict__ g1_Whh1,
    const float* __restrict__ g2_Whh0, const float* __restrict__ g2_Wih1, const float* __restrict__ g2_Whh1,
    const float* __restrict__ attn_W, const float* __restrict__ fc_W,
    unsigned short* __restrict__ wf) {
  const int id = blockIdx.x * 256 + threadIdx.x;
  if (id >= WF_TOTAL) return;
  float src;
  if (id < 2 * STACK_W) {
    const int s = id / STACK_W, r = id % STACK_W;
    const int mm = r / W1_ELEMS, e = r % W1_ELEMS;
    const int j = e & 7, lane = (e >> 3) & 63, c = (e >> 9) & 7, t = e >> 12;
    const int nt = t / 3, g = t % 3;
    const int n = nt * 16 + (lane & 15);
    const int k = c * 32 + ((lane >> 4) << 3) + j;
    const float* W = (mm == 0) ? (s ? g2_Whh0 : g1_Whh0)
                   : (mm == 1) ? (s ? g2_Wih1 : g1_Wih1)
                               : (s ? g2_Whh1 : g1_Whh1);
    src = W[(g * 256 + n) * 256 + k];
  } else if (id < B4_OFF) {
    const int e = id - B3_OFF;
    const int j = e & 7, lane = (e >> 3) & 63, c = (e >> 9) & 7, t = e >> 12;
    const int n = t * 16 + (lane & 15);
    const int k = c * 32 + ((lane >> 4) << 3) + j;
    src = (n < 256) ? attn_W[n * 512 + k] : attn_W[(n - 256) * 512 + 256 + k];
  } else {
    const int e = id - B4_OFF;
    const int j = e & 7, lane = (e >> 3) & 63, c = (e >> 9) & 15, t = e >> 13;
    const int n = t * 16 + (lane & 15);
    const int k = c * 32 + ((lane >> 4) << 3) + j;
    src = fc_W[n * 512 + k];
  }
  wf[id] = f2bf(src);
}

__global__ __launch_bounds__(NTHR, 4) void gru_attn(
    const float* __restrict__ received,
    const float* __restrict__ g1_Wih0, const float* __restrict__ g1_bih0, const float* __restrict__ g1_bhh0,
    const float* __restrict__ g1_bih1, const float* __restrict__ g1_bhh1,
    const float* __restrict__ g2_Wih0, const float* __restrict__ g2_bih0, const float* __restrict__ g2_bhh0,
    const float* __restrict__ g2_bih1, const float* __restrict__ g2_bhh1,
    const float* __restrict__ fc_b, const float* __restrict__ v_W, const float* __restrict__ out_W,
    const unsigned short* __restrict__ wf,
    unsigned short* __restrict__ buf_g, unsigned short* __restrict__ ehb_g,
    float* __restrict__ ws_p) {
  const int tid  = threadIdx.x;
  const int lane = tid & 63, wave = tid >> 6;
  const int col  = lane & 15, q = lane >> 4;
  const int s    = blockIdx.x & 1;           // stack parity -> XCD parity (L2 weight locality)
  const int b0   = (blockIdx.x >> 1) * BW;

  const float* Wih0 = s ? g2_Wih0 : g1_Wih0;
  const float* bih0 = s ? g2_bih0 : g1_bih0;
  const float* bhh0 = s ? g2_bhh0 : g1_bhh0;
  const float* bih1 = s ? g2_bih1 : g1_bih1;
  const float* bhh1 = s ? g2_bhh1 : g1_bhh1;

  const bfrag* W1  = (const bfrag*)(wf + (size_t)s * STACK_W);
  const bfrag* W2I = W1 + W1_ELEMS / 8;
  const bfrag* W2H = W2I + W1_ELEMS / 8;
  const bfrag* B3  = (const bfrag*)(wf + B3_OFF);
  const bfrag* B4  = (const bfrag*)(wf + B4_OFF);

  unsigned short* buf = buf_g + (size_t)s * BATCH * TT * 2 * HH;  // [b][j][l][h] bf16
  unsigned short* ehb = ehb_g + (size_t)s * BATCH * TT * 2 * HH;  // [b][j][l][g] bf16
  float* pp = ws_p + (size_t)s * BATCH * TT;

  // Per-lane persistent constants for output unit n = wave*16 + col
  const int nm = wave * 16 + col;
  const float wxr0 = Wih0[nm * 2],         wxr1 = Wih0[nm * 2 + 1];
  const float wxz0 = Wih0[(256 + nm) * 2], wxz1 = Wih0[(256 + nm) * 2 + 1];
  const float wxn0 = Wih0[(512 + nm) * 2], wxn1 = Wih0[(512 + nm) * 2 + 1];
  const float br0  = bih0[nm] + bhh0[nm];
  const float bz0  = bih0[256 + nm] + bhh0[256 + nm];
  const float bni0 = bih0[512 + nm], bnh0 = bhh0[512 + nm];
  const float br1  = bih1[nm] + bhh1[nm];
  const float bz1  = bih1[256 + nm] + bhh1[256 + nm];
  const float bni1 = bih1[512 + nm], bnh1 = bhh1[512 + nm];
  const float fcbv = fc_b[nm];
  const float owv  = out_W[s * HH + nm];

  // LDS (rows m = layer*4 + b, 16B-aligned pitches)
  __shared__ float          hf[8 * 260] __attribute__((aligned(16)));   // h carry fp32
  __shared__ unsigned short hb[8 * 264] __attribute__((aligned(16)));   // h carry bf16 (MFMA A)
  __shared__ unsigned short hnb[8 * 264] __attribute__((aligned(16)));  // fresh hidden bf16
  __shared__ float          es_s[8 * 264] __attribute__((aligned(16))); // s-projection, SWZ'd g
  __shared__ unsigned short cacb[8 * 264] __attribute__((aligned(16))); // context bf16 (MFMA A)
  __shared__ float          lp[TT * 4 * 2 * 2];                         // exp(logit) [j][b][l][o]
  __shared__ float          vw_s[512];                                  // v_W, SWZ'd g
  __shared__ float          cpart[2 * 2 * 4 * 256];                     // [jh][o][b][h]
  __shared__ float          pw_s[64];                                   // [wave][b]
  __shared__ float          sinv_s[8];                                  // [b][o]

  for (int x = tid; x < 8 * 260; x += NTHR) hf[x] = 0.0f;
  for (int x = tid; x < 8 * 264; x += NTHR) hb[x] = 0;
  if (tid < 512) { const int o = tid >> 8, g = tid & 255; vw_s[o * 256 + SWZ(g)] = v_W[tid]; }
  __syncthreads();

#pragma unroll 1
  for (int i = 0; i < TT; ++i) {
    float2 xv[BW];
#pragma unroll
    for (int b = 0; b < BW; b++) xv[b] = ((const float2*)received)[(size_t)(b0 + b) * TT + i];

    // ===== G1: gh0 = h0 @ Whh0^T (MFMA) -> layer-0 gates in-register -> hn0 =====
    {
      f4 aR = {0, 0, 0, 0}, aZ = {0, 0, 0, 0}, aN = {0, 0, 0, 0};
#pragma unroll
      for (int c = 0; c < 8; c++) {
        const bfrag a = (col < BW) ? *(const bfrag*)&hb[col * 264 + c * 32 + q * 8] : zero_frag();
        aR = mfma16(a, W1[((wave * 3 + 0) * 8 + c) * 64 + lane], aR);
        aZ = mfma16(a, W1[((wave * 3 + 1) * 8 + c) * 64 + lane], aZ);
        aN = mfma16(a, W1[((wave * 3 + 2) * 8 + c) * 64 + lane], aN);
      }
      if (lane < 16) {
#pragma unroll
        for (int reg = 0; reg < 4; reg++) {
          const int b = reg;
          const float r  = sigf(xv[b].x * wxr0 + xv[b].y * wxr1 + br0 + aR[reg]);
          const float z  = sigf(xv[b].x * wxz0 + xv[b].y * wxz1 + bz0 + aZ[reg]);
          const float nn = tanh_fast(xv[b].x * wxn0 + xv[b].y * wxn1 + bni0 + r * (aN[reg] + bnh0));
          const float hn0 = (1.0f - z) * nn + z * hf[b * 260 + nm];
          const unsigned short hv = f2bf(hn0);
          hnb[b * 264 + nm] = hv;
          buf[((size_t)(b0 + b) * (TT * 2) + i * 2 + 0) * HH + nm] = hv;
        }
      }
    }
    __syncthreads();

    // ===== G2: gi1 (hn0@Wih1^T) + gh1 (h1@Whh1^T) -> layer-1 gates -> hn1 + pp partial =====
    {
      f4 iR = {0,0,0,0}, iZ = {0,0,0,0}, iN = {0,0,0,0};
      f4 hR = {0,0,0,0}, hZ = {0,0,0,0}, hN = {0,0,0,0};
#pragma unroll
      for (int c = 0; c < 8; c++) {
        const bfrag ai = (col < BW) ? *(const bfrag*)&hnb[col * 264 + c * 32 + q * 8] : zero_frag();
        const bfrag ah = (col < BW) ? *(const bfrag*)&hb[(4 + col) * 264 + c * 32 + q * 8] : zero_frag();
        iR = mfma16(ai, W2I[((wave * 3 + 0) * 8 + c) * 64 + lane], iR);
        iZ = mfma16(ai, W2I[((wave * 3 + 1) * 8 + c) * 64 + lane], iZ);
        iN = mfma16(ai, W2I[((wave * 3 + 2) * 8 + c) * 64 + lane], iN);
        hR = mfma16(ah, W2H[((wave * 3 + 0) * 8 + c) * 64 + lane], hR);
        hZ = mfma16(ah, W2H[((wave * 3 + 1) * 8 + c) * 64 + lane], hZ);
        hN = mfma16(ah, W2H[((wave * 3 + 2) * 8 + c) * 64 + lane], hN);
      }
      float pv[4] = {0.f, 0.f, 0.f, 0.f};
      if (lane < 16) {
#pragma unroll
        for (int reg = 0; reg < 4; reg++) {
          const int b = reg;
          const float r  = sigf(iR[reg] + hR[reg] + br1);
          const float z  = sigf(iZ[reg] + hZ[reg] + bz1);
          const float nn = tanh_fast(iN[reg] + bni1 + r * (hN[reg] + bnh1));
          const float hn1 = (1.0f - z) * nn + z * hf[(4 + b) * 260 + nm];
          const unsigned short hv = f2bf(hn1);
          hnb[(4 + b) * 264 + nm] = hv;
          buf[((size_t)(b0 + b) * (TT * 2) + i * 2 + 1) * HH + nm] = hv;
          pv[reg] = hn1 * owv;
        }
      }
#pragma unroll
      for (int reg = 0; reg < 4; reg++) {
#pragma unroll
        for (int d = 1; d < 16; d <<= 1) pv[reg] += __shfl_xor(pv[reg], d, 64);
      }
      if (lane == 0) {
#pragma unroll
        for (int reg = 0; reg < 4; reg++) pw_s[wave * 4 + reg] = pv[reg];
      }
    }
    __syncthreads();

    // ===== G3: hn(l,b) @ [attnW_s | attnW_h]^T -> es (LDS, SWZ) / ehb (global bf16); pp fold =====
    {
#pragma unroll
      for (int tt = 0; tt < 2; tt++) {
        const int t = wave * 2 + tt;
        f4 acc = {0, 0, 0, 0};
#pragma unroll
        for (int c = 0; c < 8; c++) {
          const bfrag a = (col < 8) ? *(const bfrag*)&hnb[col * 264 + c * 32 + q * 8] : zero_frag();
          acc = mfma16(a, B3[(t * 8 + c) * 64 + lane], acc);
        }
        if (lane < 32) {
          const int n = t * 16 + col;
#pragma unroll
          for (int reg = 0; reg < 4; reg++) {
            const int m = q * 4 + reg;       // 0..7 = l*4+b
            const int l = m >> 2, b = m & 3;
            if (t < 16) es_s[(b * 2 + l) * 264 + SWZ(n)] = acc[reg];
            else ehb[((size_t)(b0 + b) * (TT * 2) + i * 2 + l) * HH + (n - 256)] = f2bf(acc[reg]);
          }
        }
      }
      if (tid < 4) {
        float ss = 0.0f;
#pragma unroll
        for (int w = 0; w < 16; w++) ss += pw_s[w * 4 + tid];
        pp[(size_t)(b0 + tid) * TT + i] = ss;
      }
    }
    __syncthreads();

    // ===== energy: e = exp(sum_g v*tanh(es+eh)) for (b,l,j<=i); max-free (|logit|<=16) =====
    {
      const int nslot = 64 * (i + 1);
      for (int slot = tid; slot < nslot; slot += NTHR) {
        const int g8 = slot & 7;
        const int b  = (slot >> 3) & 3;
        const int l  = (slot >> 5) & 1;
        const int j  = slot >> 6;
        const uv4* ep = (const uv4*)(ehb + ((size_t)(b0 + b) * (TT * 2) + j * 2 + l) * HH + g8 * 32);
        const int eb = (b * 2 + l) * 264;
        float l0 = 0.0f, l1 = 0.0f;
#pragma unroll
        for (int u = 0; u < 4; u++) {
          const uv4 uu = __builtin_nontemporal_load(ep + u);
#pragma unroll
          for (int k = 0; k < 4; k++) {
            const int m = u * 8 + k * 2;
            const float e0 = tanh_fast(es_s[eb + (m * 8 + g8)] + bf_lo(uu[k]));
            const float e1 = tanh_fast(es_s[eb + ((m + 1) * 8 + g8)] + bf_hi(uu[k]));
            l0 = fmaf(e0, vw_s[m * 8 + g8], fmaf(e1, vw_s[(m + 1) * 8 + g8], l0));
            l1 = fmaf(e0, vw_s[256 + m * 8 + g8], fmaf(e1, vw_s[256 + (m + 1) * 8 + g8], l1));
          }
        }
#pragma unroll
        for (int d = 1; d < 8; d <<= 1) { l0 += __shfl_xor(l0, d, 64); l1 += __shfl_xor(l1, d, 64); }
        if (g8 == 0) {
          lp[((j * 4 + b) * 2 + l) * 2 + 0] = __expf(l0);
          lp[((j * 4 + b) * 2 + l) * 2 + 1] = __expf(l1);
        }
      }
    }
    __syncthreads();

    // ===== sinv (waves 0-7) + context partials (all, j split even/odd, uint=2h loads) =====
    {
      if (wave < 8) {
        const int b = wave >> 1, o = wave & 1;
        float sa = 0.0f;
        if (lane <= i)
          sa = lp[((lane * 4 + b) * 2 + 0) * 2 + o] + lp[((lane * 4 + b) * 2 + 1) * 2 + o];
#pragma unroll
        for (int d = 1; d < 64; d <<= 1) sa += __shfl_xor(sa, d, 64);
        if (lane == 0) sinv_s[b * 2 + o] = rcpf(sa);
      }
      const int b = tid >> 8, jh = (tid >> 7) & 1, h2 = tid & 127;
      const uint_t* bp = (const uint_t*)(buf + ((size_t)(b0 + b) * (TT * 2)) * HH) + h2;
      float c00 = 0.f, c01 = 0.f, c10 = 0.f, c11 = 0.f;
      for (int j = jh; j <= i; j += 2) {
#pragma unroll
        for (int l = 0; l < 2; l++) {
          const uint_t u = __builtin_nontemporal_load(bp + (j * 2 + l) * 128);
          const float e0 = lp[((j * 4 + b) * 2 + l) * 2 + 0];
          const float e1 = lp[((j * 4 + b) * 2 + l) * 2 + 1];
          const float v0 = bf_lo(u), v1 = bf_hi(u);
          c00 = fmaf(e0, v0, c00); c01 = fmaf(e0, v1, c01);
          c10 = fmaf(e1, v0, c10); c11 = fmaf(e1, v1, c11);
        }
      }
      float* cp0 = &cpart[((jh * 2 + 0) * 4 + b) * 256 + h2 * 2];
      cp0[0] = c00; cp0[1] = c01;
      float* cp1 = &cpart[((jh * 2 + 1) * 4 + b) * 256 + h2 * 2];
      cp1[0] = c10; cp1[1] = c11;
    }
    __syncthreads();

    // ===== fold context halves, normalize -> cacb bf16 =====
    {
#pragma unroll
      for (int r = 0; r < 2; r++) {
        const int idx = tid + r * NTHR;
        const int o = idx >> 10, b = (idx >> 8) & 3, h = idx & 255;
        const float v = (cpart[(o * 4 + b) * 256 + h] + cpart[((2 + o) * 4 + b) * 256 + h]) *
                        sinv_s[b * 2 + o];
        cacb[(o * 4 + b) * 264 + h] = f2bf(v);
      }
    }
    __syncthreads();

    // ===== G4: h = [cac|hn] @ fc_W^T + fc_b (K=512) -> new carry (fp32 + bf16) =====
    {
      f4 acc = {0, 0, 0, 0};
#pragma unroll
      for (int c = 0; c < 16; c++) {
        bfrag a;
        if (col < 8) {
          if (c < 8) a = *(const bfrag*)&cacb[col * 264 + c * 32 + q * 8];
          else       a = *(const bfrag*)&hnb[col * 264 + (c - 8) * 32 + q * 8];
        } else a = zero_frag();
        acc = mfma16(a, B4[(wave * 16 + c) * 64 + lane], acc);
      }
      if (lane < 32) {
#pragma unroll
        for (int reg = 0; reg < 4; reg++) {
          const int m = q * 4 + reg;        // 0..7 = o*4+b
          const float v = acc[reg] + fcbv;
          hf[m * 260 + nm] = v;
          hb[m * 264 + nm] = f2bf(v);
        }
      }
    }
    __syncthreads();
  }
}

__global__ __launch_bounds__(256) void final_combine(const float* __restrict__ ws_p,
                                                     const float* __restrict__ out_b,
                                                     float* __restrict__ out) {
  const int gidx = blockIdx.x * blockDim.x + threadIdx.x;
  if (gidx >= BATCH * TT) return;
  const int b = gidx >> 6;
  const int t = gidx & 63;
  const int idx = (t >= TT - DD - 1) ? (TT - 1) : (t + DD);
  const float* p1 = ws_p;
  const float* p2 = ws_p + (size_t)BATCH * TT;
  const float v = p1[(size_t)b * TT + t] + p2[(size_t)b * TT + idx] + out_b[0];
  out[gidx] = 1.0f / (1.0f + __expf(-v));
}

extern "C" void kernel_launch(void* const* d_in, const int* in_sizes, int n_in,
                              void* d_out, int out_size, void* d_ws, size_t ws_size,
                              hipStream_t stream) {
  const float* received = (const float*)d_in[0];
  const float* g1_Wih0 = (const float*)d_in[1];
  const float* g1_Whh0 = (const float*)d_in[2];
  const float* g1_bih0 = (const float*)d_in[3];
  const float* g1_bhh0 = (const float*)d_in[4];
  const float* g1_Wih1 = (const float*)d_in[5];
  const float* g1_Whh1 = (const float*)d_in[6];
  const float* g1_bih1 = (const float*)d_in[7];
  const float* g1_bhh1 = (const float*)d_in[8];
  const float* g2_Wih0 = (const float*)d_in[9];
  const float* g2_Whh0 = (const float*)d_in[10];
  const float* g2_bih0 = (const float*)d_in[11];
  const float* g2_bhh0 = (const float*)d_in[12];
  const float* g2_Wih1 = (const float*)d_in[13];
  const float* g2_Whh1 = (const float*)d_in[14];
  const float* g2_bih1 = (const float*)d_in[15];
  const float* g2_bhh1 = (const float*)d_in[16];
  const float* fc_W   = (const float*)d_in[17];
  const float* fc_b   = (const float*)d_in[18];
  const float* attn_W = (const float*)d_in[19];
  const float* v_W    = (const float*)d_in[20];
  const float* out_W  = (const float*)d_in[21];
  const float* out_b  = (const float*)d_in[22];

  // ws layout: fp32 pp[2*B*T] | bf16 buf[2*B*T*2*H] | bf16 ehb[same] | bf16 wf[WF_TOTAL]
  float* ws_p = (float*)d_ws;
  unsigned short* buf = (unsigned short*)(ws_p + 2 * BATCH * TT);
  unsigned short* ehb = buf + (size_t)2 * BATCH * TT * 2 * HH;
  unsigned short* wf  = ehb + (size_t)2 * BATCH * TT * 2 * HH;

  hipLaunchKernelGGL(prep_weights, dim3((WF_TOTAL + 255) / 256), dim3(256), 0, stream,
                     g1_Whh0, g1_Wih1, g1_Whh1, g2_Whh0, g2_Wih1, g2_Whh1,
                     attn_W, fc_W, wf);

  hipLaunchKernelGGL(gru_attn, dim3(NBLK), dim3(NTHR), 0, stream,
                     received,
                     g1_Wih0, g1_bih0, g1_bhh0, g1_bih1, g1_bhh1,
                     g2_Wih0, g2_bih0, g2_bhh0, g2_bih1, g2_bhh1,
                     fc_b, v_W, out_W, wf, buf, ehb, ws_p);

  hipLaunchKernelGGL(final_combine, dim3((BATCH * TT + 255) / 256), dim3(256), 0, stream,
                     ws_p, out_b, (float*)d_out);
}

// Round 5
// 5926.101 us; speedup vs baseline: 1.6859x; 1.0438x over previous
//
#include <hip/hip_runtime.h>

// Problem constants
#define BATCH 256
#define TT    64
#define HH    256
#define DD    8

// Tiling: 2 stacks * 64 batch-blocks of BW=4 -> 128 WGs, 512 thr (8 waves)
#define BW    4
#define NTHR  512
#define NBLK  (2 * (BATCH / BW))

typedef __attribute__((ext_vector_type(8))) short bfrag;   // 8 bf16 (MFMA A/B operand)
typedef __attribute__((ext_vector_type(4))) float f4;      // MFMA C/D
typedef __attribute__((ext_vector_type(4))) unsigned int uv4;
typedef __attribute__((ext_vector_type(2))) unsigned int uv2;

#define SWZ(g) ((((g) & 31) << 3) | ((g) >> 5))

__device__ __forceinline__ float rcpf(float x) { return __builtin_amdgcn_rcpf(x); }
__device__ __forceinline__ float sigf(float x) { return rcpf(1.0f + __expf(-x)); }
__device__ __forceinline__ float tanh_fast(float x) {
  const float e = __expf(-2.0f * x);
  return __builtin_fmaf(2.0f, rcpf(1.0f + e), -1.0f);
}
__device__ __forceinline__ unsigned short f2bf(float f) {
  union { float f; unsigned int u; } v; v.f = f;
  return (unsigned short)((v.u + 0x7fffu + ((v.u >> 16) & 1u)) >> 16);
}
__device__ __forceinline__ float bf_lo(unsigned int u) {
  union { unsigned int u; float f; } v; v.u = u << 16; return v.f;
}
__device__ __forceinline__ float bf_hi(unsigned int u) {
  union { unsigned int u; float f; } v; v.u = u & 0xffff0000u; return v.f;
}
__device__ __forceinline__ bfrag zero_frag() {
  bfrag r;
#pragma unroll
  for (int x = 0; x < 8; x++) r[x] = 0;
  return r;
}
__device__ __forceinline__ f4 mfma16(bfrag a, bfrag b, f4 c) {
  return __builtin_amdgcn_mfma_f32_16x16x32_bf16(a, b, c, 0, 0, 0);
}

// ---------- weight fragment layout (UNCHANGED from round 4) ----------
#define W1_ELEMS  196608
#define STACK_W   (3 * W1_ELEMS)
#define B3_OFF    (2 * STACK_W)
#define B4_OFF    (B3_OFF + 131072)
#define WF_TOTAL  (B4_OFF + 131072)

__global__ __launch_bounds__(256) void prep_weights(
    const float* __restrict__ g1_Whh0, const float* __restrict__ g1_Wih1, const float* __restrict__ g1_Whh1,
    const float* __restrict__ g2_Whh0, const float* __restrict__ g2_Wih1, const float* __restrict__ g2_Whh1,
    const float* __restrict__ attn_W, const float* __restrict__ fc_W,
    unsigned short* __restrict__ wf) {
  const int id = blockIdx.x * 256 + threadIdx.x;
  if (id >= WF_TOTAL) return;
  float src;
  if (id < 2 * STACK_W) {
    const int s = id / STACK_W, r = id % STACK_W;
    const int mm = r / W1_ELEMS, e = r % W1_ELEMS;
    const int j = e & 7, lane = (e >> 3) & 63, c = (e >> 9) & 7, t = e >> 12;
    const int nt = t / 3, g = t % 3;
    const int n = nt * 16 + (lane & 15);
    const int k = c * 32 + ((lane >> 4) << 3) + j;
    const float* W = (mm == 0) ? (s ? g2_Whh0 : g1_Whh0)
                   : (mm == 1) ? (s ? g2_Wih1 : g1_Wih1)
                               : (s ? g2_Whh1 : g1_Whh1);
    src = W[(g * 256 + n) * 256 + k];
  } else if (id < B4_OFF) {
    const int e = id - B3_OFF;
    const int j = e & 7, lane = (e >> 3) & 63, c = (e >> 9) & 7, t = e >> 12;
    const int n = t * 16 + (lane & 15);
    const int k = c * 32 + ((lane >> 4) << 3) + j;
    src = (n < 256) ? attn_W[n * 512 + k] : attn_W[(n - 256) * 512 + 256 + k];
  } else {
    const int e = id - B4_OFF;
    const int j = e & 7, lane = (e >> 3) & 63, c = (e >> 9) & 15, t = e >> 13;
    const int n = t * 16 + (lane & 15);
    const int k = c * 32 + ((lane >> 4) << 3) + j;
    src = fc_W[n * 512 + k];
  }
  wf[id] = f2bf(src);
}

__global__ __launch_bounds__(NTHR, 2) void gru_attn(
    const float* __restrict__ received,
    const float* __restrict__ g1_Wih0, const float* __restrict__ g1_bih0, const float* __restrict__ g1_bhh0,
    const float* __restrict__ g1_bih1, const float* __restrict__ g1_bhh1,
    const float* __restrict__ g2_Wih0, const float* __restrict__ g2_bih0, const float* __restrict__ g2_bhh0,
    const float* __restrict__ g2_bih1, const float* __restrict__ g2_bhh1,
    const float* __restrict__ fc_b, const float* __restrict__ v_W, const float* __restrict__ out_W,
    const unsigned short* __restrict__ wf,
    unsigned short* __restrict__ buf_g, unsigned short* __restrict__ ehb_g,
    float* __restrict__ ws_p) {
  const int tid  = threadIdx.x;
  const int lane = tid & 63, wave = tid >> 6;      // 8 waves
  const int col  = lane & 15, q = lane >> 4;
  const int s    = blockIdx.x & 1;                 // stack parity -> XCD parity
  const int b0   = (blockIdx.x >> 1) * BW;

  const float* Wih0 = s ? g2_Wih0 : g1_Wih0;
  const float* bih0 = s ? g2_bih0 : g1_bih0;
  const float* bhh0 = s ? g2_bhh0 : g1_bhh0;
  const float* bih1 = s ? g2_bih1 : g1_bih1;
  const float* bhh1 = s ? g2_bhh1 : g1_bhh1;

  const bfrag* W1  = (const bfrag*)(wf + (size_t)s * STACK_W);
  const bfrag* W2I = W1 + W1_ELEMS / 8;
  const bfrag* W2H = W2I + W1_ELEMS / 8;
  const bfrag* B3  = (const bfrag*)(wf + B3_OFF);
  const bfrag* B4  = (const bfrag*)(wf + B4_OFF);

  unsigned short* buf = buf_g + (size_t)s * BATCH * TT * 2 * HH;
  unsigned short* ehb = ehb_g + (size_t)s * BATCH * TT * 2 * HH;
  float* pp = ws_p + (size_t)s * BATCH * TT;

  // Per-lane persistent constants for TWO unit rounds: nm = (wave + 8*r2)*16 + col
  float wxr0v[2], wxr1v[2], wxz0v[2], wxz1v[2], wxn0v[2], wxn1v[2];
  float br0v[2], bz0v[2], bni0v[2], bnh0v[2];
  float br1v[2], bz1v[2], bni1v[2], bnh1v[2];
  float fcbv[2], owvv[2];
#pragma unroll
  for (int r2 = 0; r2 < 2; r2++) {
    const int nm = (wave + 8 * r2) * 16 + col;
    wxr0v[r2] = Wih0[nm * 2];         wxr1v[r2] = Wih0[nm * 2 + 1];
    wxz0v[r2] = Wih0[(256 + nm) * 2]; wxz1v[r2] = Wih0[(256 + nm) * 2 + 1];
    wxn0v[r2] = Wih0[(512 + nm) * 2]; wxn1v[r2] = Wih0[(512 + nm) * 2 + 1];
    br0v[r2]  = bih0[nm] + bhh0[nm];
    bz0v[r2]  = bih0[256 + nm] + bhh0[256 + nm];
    bni0v[r2] = bih0[512 + nm]; bnh0v[r2] = bhh0[512 + nm];
    br1v[r2]  = bih1[nm] + bhh1[nm];
    bz1v[r2]  = bih1[256 + nm] + bhh1[256 + nm];
    bni1v[r2] = bih1[512 + nm]; bnh1v[r2] = bhh1[512 + nm];
    fcbv[r2]  = fc_b[nm];
    owvv[r2]  = out_W[s * HH + nm];
  }

  __shared__ float          hf[8 * 260] __attribute__((aligned(16)));
  __shared__ unsigned short hb[8 * 264] __attribute__((aligned(16)));
  __shared__ unsigned short hnb[8 * 264] __attribute__((aligned(16)));
  __shared__ float          es_s[8 * 264] __attribute__((aligned(16)));
  __shared__ unsigned short cacb[8 * 264] __attribute__((aligned(16)));
  __shared__ float          lp[TT * 4 * 2 * 2];       // exp(logit) [j][b][l][o]
  __shared__ float          vw_s[512];                // v_W SWZ'd
  __shared__ float          cpart[2 * 2 * 4 * 256] __attribute__((aligned(16)));
  __shared__ float          pw_s[32];                 // [wave][b]
  __shared__ float          sinv_s[8];

  for (int x = tid; x < 8 * 260; x += NTHR) hf[x] = 0.0f;
  for (int x = tid; x < 8 * 264; x += NTHR) hb[x] = 0;
  { const int o = tid >> 8, g = tid & 255; vw_s[o * 256 + SWZ(g)] = v_W[tid]; }
  __syncthreads();

#pragma unroll 1
  for (int i = 0; i < TT; ++i) {
    float2 xv[BW];
#pragma unroll
    for (int b = 0; b < BW; b++) xv[b] = ((const float2*)received)[(size_t)(b0 + b) * TT + i];

    // ===== G1: gh0 = h0 @ Whh0^T -> layer-0 gates -> hn0 =====
    {
      bfrag a0[8];
#pragma unroll
      for (int c = 0; c < 8; c++)
        a0[c] = (col < BW) ? *(const bfrag*)&hb[col * 264 + c * 32 + q * 8] : zero_frag();
#pragma unroll
      for (int r2 = 0; r2 < 2; r2++) {
        const int nt16 = wave + 8 * r2;
        bfrag bb[24];
#pragma unroll
        for (int c = 0; c < 8; c++) {
          bb[c]      = W1[((nt16 * 3 + 0) * 8 + c) * 64 + lane];
          bb[8 + c]  = W1[((nt16 * 3 + 1) * 8 + c) * 64 + lane];
          bb[16 + c] = W1[((nt16 * 3 + 2) * 8 + c) * 64 + lane];
        }
        f4 aR = {0, 0, 0, 0}, aZ = {0, 0, 0, 0}, aN = {0, 0, 0, 0};
#pragma unroll
        for (int c = 0; c < 8; c++) {
          aR = mfma16(a0[c], bb[c], aR);
          aZ = mfma16(a0[c], bb[8 + c], aZ);
          aN = mfma16(a0[c], bb[16 + c], aN);
        }
        if (lane < 16) {
          const int nm = nt16 * 16 + col;
#pragma unroll
          for (int reg = 0; reg < 4; reg++) {
            const int b = reg;
            const float rr = sigf(xv[b].x * wxr0v[r2] + xv[b].y * wxr1v[r2] + br0v[r2] + aR[reg]);
            const float zz = sigf(xv[b].x * wxz0v[r2] + xv[b].y * wxz1v[r2] + bz0v[r2] + aZ[reg]);
            const float nn = tanh_fast(xv[b].x * wxn0v[r2] + xv[b].y * wxn1v[r2] + bni0v[r2] +
                                       rr * (aN[reg] + bnh0v[r2]));
            const float hn0 = (1.0f - zz) * nn + zz * hf[b * 260 + nm];
            const unsigned short hv = f2bf(hn0);
            hnb[b * 264 + nm] = hv;
            buf[((size_t)(b0 + b) * (TT * 2) + i * 2 + 0) * HH + nm] = hv;
          }
        }
      }
    }
    __syncthreads();

    // ===== G2: gi1 + gh1 -> layer-1 gates -> hn1 + pp partial =====
    {
      bfrag ai[8], ah[8];
#pragma unroll
      for (int c = 0; c < 8; c++) {
        ai[c] = (col < BW) ? *(const bfrag*)&hnb[col * 264 + c * 32 + q * 8] : zero_frag();
        ah[c] = (col < BW) ? *(const bfrag*)&hb[(4 + col) * 264 + c * 32 + q * 8] : zero_frag();
      }
      float pv[4] = {0.f, 0.f, 0.f, 0.f};
#pragma unroll
      for (int r2 = 0; r2 < 2; r2++) {
        const int nt16 = wave + 8 * r2;
        bfrag bb[24];
#pragma unroll
        for (int c = 0; c < 8; c++) {
          bb[c]      = W2I[((nt16 * 3 + 0) * 8 + c) * 64 + lane];
          bb[8 + c]  = W2I[((nt16 * 3 + 1) * 8 + c) * 64 + lane];
          bb[16 + c] = W2I[((nt16 * 3 + 2) * 8 + c) * 64 + lane];
        }
        f4 iR = {0, 0, 0, 0}, iZ = {0, 0, 0, 0}, iN = {0, 0, 0, 0};
#pragma unroll
        for (int c = 0; c < 8; c++) {
          iR = mfma16(ai[c], bb[c], iR);
          iZ = mfma16(ai[c], bb[8 + c], iZ);
          iN = mfma16(ai[c], bb[16 + c], iN);
        }
#pragma unroll
        for (int c = 0; c < 8; c++) {
          bb[c]      = W2H[((nt16 * 3 + 0) * 8 + c) * 64 + lane];
          bb[8 + c]  = W2H[((nt16 * 3 + 1) * 8 + c) * 64 + lane];
          bb[16 + c] = W2H[((nt16 * 3 + 2) * 8 + c) * 64 + lane];
        }
        f4 hR = {0, 0, 0, 0}, hZ = {0, 0, 0, 0}, hN = {0, 0, 0, 0};
#pragma unroll
        for (int c = 0; c < 8; c++) {
          hR = mfma16(ah[c], bb[c], hR);
          hZ = mfma16(ah[c], bb[8 + c], hZ);
          hN = mfma16(ah[c], bb[16 + c], hN);
        }
        if (lane < 16) {
          const int nm = nt16 * 16 + col;
#pragma unroll
          for (int reg = 0; reg < 4; reg++) {
            const int b = reg;
            const float rr = sigf(iR[reg] + hR[reg] + br1v[r2]);
            const float zz = sigf(iZ[reg] + hZ[reg] + bz1v[r2]);
            const float nn = tanh_fast(iN[reg] + bni1v[r2] + rr * (hN[reg] + bnh1v[r2]));
            const float hn1 = (1.0f - zz) * nn + zz * hf[(4 + b) * 260 + nm];
            const unsigned short hv = f2bf(hn1);
            hnb[(4 + b) * 264 + nm] = hv;
            buf[((size_t)(b0 + b) * (TT * 2) + i * 2 + 1) * HH + nm] = hv;
            pv[reg] += hn1 * owvv[r2];
          }
        }
      }
#pragma unroll
      for (int reg = 0; reg < 4; reg++) {
#pragma unroll
        for (int d = 1; d < 16; d <<= 1) pv[reg] += __shfl_xor(pv[reg], d, 64);
      }
      if (lane == 0) {
#pragma unroll
        for (int reg = 0; reg < 4; reg++) pw_s[wave * 4 + reg] = pv[reg];
      }
    }
    __syncthreads();

    // ===== G3: es/eh projections; pp fold =====
    {
      bfrag a3[8];
#pragma unroll
      for (int c = 0; c < 8; c++)
        a3[c] = (col < 8) ? *(const bfrag*)&hnb[col * 264 + c * 32 + q * 8] : zero_frag();
#pragma unroll
      for (int tt = 0; tt < 4; tt++) {
        const int t = wave * 4 + tt;
        bfrag bb[8];
#pragma unroll
        for (int c = 0; c < 8; c++) bb[c] = B3[(t * 8 + c) * 64 + lane];
        f4 acc = {0, 0, 0, 0};
#pragma unroll
        for (int c = 0; c < 8; c++) acc = mfma16(a3[c], bb[c], acc);
        if (lane < 32) {
          const int n = t * 16 + col;
#pragma unroll
          for (int reg = 0; reg < 4; reg++) {
            const int m = q * 4 + reg;   // 0..7 = l*4+b
            const int l = m >> 2, b = m & 3;
            if (t < 16) es_s[(b * 2 + l) * 264 + SWZ(n)] = acc[reg];
            else ehb[((size_t)(b0 + b) * (TT * 2) + i * 2 + l) * HH + (n - 256)] = f2bf(acc[reg]);
          }
        }
      }
      if (tid < 4) {
        float ss = 0.0f;
#pragma unroll
        for (int w = 0; w < 8; w++) ss += pw_s[w * 4 + tid];
        pp[(size_t)(b0 + tid) * TT + i] = ss;
      }
    }
    __syncthreads();

    // ===== energy: exp(sum_g v*tanh(es+eh)) with 2-stage load pipeline =====
    {
      const int nslot = 64 * (i + 1);
      int slot = tid;
      uv4 cur[4];
      if (slot < nslot) {
        const uv4* ep = (const uv4*)(ehb + ((size_t)(b0 + ((slot >> 3) & 3)) * (TT * 2) +
                                            (slot >> 6) * 2 + ((slot >> 5) & 1)) * HH + (slot & 7) * 32);
#pragma unroll
        for (int u = 0; u < 4; u++) cur[u] = __builtin_nontemporal_load(ep + u);
      }
      for (; slot < nslot; slot += NTHR) {
        const int snext = slot + NTHR;
        uv4 nxt[4];
        if (snext < nslot) {
          const uv4* ep2 = (const uv4*)(ehb + ((size_t)(b0 + ((snext >> 3) & 3)) * (TT * 2) +
                                               (snext >> 6) * 2 + ((snext >> 5) & 1)) * HH + (snext & 7) * 32);
#pragma unroll
          for (int u = 0; u < 4; u++) nxt[u] = __builtin_nontemporal_load(ep2 + u);
        } else {
#pragma unroll
          for (int u = 0; u < 4; u++) nxt[u] = cur[u];
        }
        const int g8 = slot & 7;
        const int b  = (slot >> 3) & 3;
        const int l  = (slot >> 5) & 1;
        const int j  = slot >> 6;
        const int eb = (b * 2 + l) * 264;
        float l0 = 0.0f, l1 = 0.0f;
#pragma unroll
        for (int u = 0; u < 4; u++) {
#pragma unroll
          for (int k = 0; k < 4; k++) {
            const int m = u * 8 + k * 2;
            const float e0 = tanh_fast(es_s[eb + (m * 8 + g8)] + bf_lo(cur[u][k]));
            const float e1 = tanh_fast(es_s[eb + ((m + 1) * 8 + g8)] + bf_hi(cur[u][k]));
            l0 = fmaf(e0, vw_s[m * 8 + g8], fmaf(e1, vw_s[(m + 1) * 8 + g8], l0));
            l1 = fmaf(e0, vw_s[256 + m * 8 + g8], fmaf(e1, vw_s[256 + (m + 1) * 8 + g8], l1));
          }
        }
#pragma unroll
        for (int d = 1; d < 8; d <<= 1) { l0 += __shfl_xor(l0, d, 64); l1 += __shfl_xor(l1, d, 64); }
        if (g8 == 0) {
          lp[((j * 4 + b) * 2 + l) * 2 + 0] = __expf(l0);
          lp[((j * 4 + b) * 2 + l) * 2 + 1] = __expf(l1);
        }
#pragma unroll
        for (int u = 0; u < 4; u++) cur[u] = nxt[u];
      }
    }
    __syncthreads();

    // ===== sinv (all 8 waves) + context (uint2 loads, 2-way j-split, 4-load lookahead) =====
    {
      {
        const int b = wave >> 1, o = wave & 1;
        const int jl2 = 2 * (i + 1);
        const int jl0 = lane, jl1 = lane + 64;
        float sa = 0.0f;
        if (jl0 < jl2) sa += lp[((jl0 >> 1) * 4 + b) * 4 + (jl0 & 1) * 2 + o];
        if (jl1 < jl2) sa += lp[((jl1 >> 1) * 4 + b) * 4 + (jl1 & 1) * 2 + o];
#pragma unroll
        for (int d = 1; d < 64; d <<= 1) sa += __shfl_xor(sa, d, 64);
        if (lane == 0) sinv_s[b * 2 + o] = rcpf(sa);
      }
      const int h4   = tid & 63;           // uint2 slice (4 h-values)
      const int jpar = (tid >> 6) & 1;
      const int cb   = tid >> 7;           // batch 0..3
      const uv2* bp = (const uv2*)(buf + ((size_t)(b0 + cb) * (TT * 2)) * HH);
      float c00 = 0.f, c01 = 0.f, c02 = 0.f, c03 = 0.f;
      float c10 = 0.f, c11 = 0.f, c12 = 0.f, c13 = 0.f;
      uv2 aj0 = {0, 0}, aj1 = {0, 0}, bj0 = {0, 0}, bj1 = {0, 0};
      int j = jpar;
      if (j <= i) {
        aj0 = __builtin_nontemporal_load(bp + (j * 2 + 0) * 64 + h4);
        aj1 = __builtin_nontemporal_load(bp + (j * 2 + 1) * 64 + h4);
        // prefetch j+2 (address valid inside workspace even past i)
        bj0 = __builtin_nontemporal_load(bp + ((j + 2) * 2 + 0) * 64 + h4);
        bj1 = __builtin_nontemporal_load(bp + ((j + 2) * 2 + 1) * 64 + h4);
      }
      for (; j <= i; j += 2) {
        uv2 cj0 = {0, 0}, cj1 = {0, 0};
        if (j + 4 <= i) {
          cj0 = __builtin_nontemporal_load(bp + ((j + 4) * 2 + 0) * 64 + h4);
          cj1 = __builtin_nontemporal_load(bp + ((j + 4) * 2 + 1) * 64 + h4);
        }
#pragma unroll
        for (int l = 0; l < 2; l++) {
          const uv2 u = l ? aj1 : aj0;
          const float e0 = lp[((j * 4 + cb) * 2 + l) * 2 + 0];
          const float e1 = lp[((j * 4 + cb) * 2 + l) * 2 + 1];
          const float v0 = bf_lo(u[0]), v1 = bf_hi(u[0]);
          const float v2 = bf_lo(u[1]), v3 = bf_hi(u[1]);
          c00 = fmaf(e0, v0, c00); c01 = fmaf(e0, v1, c01);
          c02 = fmaf(e0, v2, c02); c03 = fmaf(e0, v3, c03);
          c10 = fmaf(e1, v0, c10); c11 = fmaf(e1, v1, c11);
          c12 = fmaf(e1, v2, c12); c13 = fmaf(e1, v3, c13);
        }
        aj0 = bj0; aj1 = bj1; bj0 = cj0; bj1 = cj1;
      }
      ((float4*)&cpart[((jpar * 2 + 0) * 4 + cb) * 256])[h4] = make_float4(c00, c01, c02, c03);
      ((float4*)&cpart[((jpar * 2 + 1) * 4 + cb) * 256])[h4] = make_float4(c10, c11, c12, c13);
    }
    __syncthreads();

    // ===== fold context halves, normalize -> cacb bf16 =====
    for (int x = tid; x < 2 * BW * HH; x += NTHR) {
      const int g = x & 255, b = (x >> 8) & 3, o = x >> 10;
      const float v = (cpart[(o * 4 + b) * 256 + g] + cpart[((2 + o) * 4 + b) * 256 + g]) *
                      sinv_s[b * 2 + o];
      cacb[(o * 4 + b) * 264 + g] = f2bf(v);
    }
    __syncthreads();

    // ===== G4: h = [cac|hn] @ fc_W^T + fc_b (K=512) -> new carry =====
    {
      bfrag a4[16];
      if (col < 8) {
#pragma unroll
        for (int c = 0; c < 8; c++) {
          a4[c]     = *(const bfrag*)&cacb[col * 264 + c * 32 + q * 8];
          a4[c + 8] = *(const bfrag*)&hnb[col * 264 + c * 32 + q * 8];
        }
      } else {
#pragma unroll
        for (int c = 0; c < 16; c++) a4[c] = zero_frag();
      }
#pragma unroll
      for (int r2 = 0; r2 < 2; r2++) {
        const int t16 = wave + 8 * r2;
        bfrag bb[16];
#pragma unroll
        for (int c = 0; c < 16; c++) bb[c] = B4[(t16 * 16 + c) * 64 + lane];
        f4 acc = {0, 0, 0, 0};
#pragma unroll
        for (int c = 0; c < 16; c++) acc = mfma16(a4[c], bb[c], acc);
        if (lane < 32) {
          const int nm = t16 * 16 + col;
#pragma unroll
          for (int reg = 0; reg < 4; reg++) {
            const int m = q * 4 + reg;   // 0..7 = o*4+b
            const float v = acc[reg] + fcbv[r2];
            hf[m * 260 + nm] = v;
            hb[m * 264 + nm] = f2bf(v);
          }
        }
      }
    }
    __syncthreads();
  }
}

__global__ __launch_bounds__(256) void final_combine(const float* __restrict__ ws_p,
                                                     const float* __restrict__ out_b,
                                                     float* __restrict__ out) {
  const int gidx = blockIdx.x * blockDim.x + threadIdx.x;
  if (gidx >= BATCH * TT) return;
  const int b = gidx >> 6;
  const int t = gidx & 63;
  const int idx = (t >= TT - DD - 1) ? (TT - 1) : (t + DD);
  const float* p1 = ws_p;
  const float* p2 = ws_p + (size_t)BATCH * TT;
  const float v = p1[(size_t)b * TT + t] + p2[(size_t)b * TT + idx] + out_b[0];
  out[gidx] = 1.0f / (1.0f + __expf(-v));
}

extern "C" void kernel_launch(void* const* d_in, const int* in_sizes, int n_in,
                              void* d_out, int out_size, void* d_ws, size_t ws_size,
                              hipStream_t stream) {
  const float* received = (const float*)d_in[0];
  const float* g1_Wih0 = (const float*)d_in[1];
  const float* g1_Whh0 = (const float*)d_in[2];
  const float* g1_bih0 = (const float*)d_in[3];
  const float* g1_bhh0 = (const float*)d_in[4];
  const float* g1_Wih1 = (const float*)d_in[5];
  const float* g1_Whh1 = (const float*)d_in[6];
  const float* g1_bih1 = (const float*)d_in[7];
  const float* g1_bhh1 = (const float*)d_in[8];
  const float* g2_Wih0 = (const float*)d_in[9];
  const float* g2_Whh0 = (const float*)d_in[10];
  const float* g2_bih0 = (const float*)d_in[11];
  const float* g2_bhh0 = (const float*)d_in[12];
  const float* g2_Wih1 = (const float*)d_in[13];
  const float* g2_Whh1 = (const float*)d_in[14];
  const float* g2_bih1 = (const float*)d_in[15];
  const float* g2_bhh1 = (const float*)d_in[16];
  const float* fc_W   = (const float*)d_in[17];
  const float* fc_b   = (const float*)d_in[18];
  const float* attn_W = (const float*)d_in[19];
  const float* v_W    = (const float*)d_in[20];
  const float* out_W  = (const float*)d_in[21];
  const float* out_b  = (const float*)d_in[22];

  // ws layout: fp32 pp[2*B*T] | bf16 buf[2*B*T*2*H] | bf16 ehb[same] | bf16 wf[WF_TOTAL]
  float* ws_p = (float*)d_ws;
  unsigned short* buf = (unsigned short*)(ws_p + 2 * BATCH * TT);
  unsigned short* ehb = buf + (size_t)2 * BATCH * TT * 2 * HH;
  unsigned short* wf  = ehb + (size_t)2 * BATCH * TT * 2 * HH;

  hipLaunchKernelGGL(prep_weights, dim3((WF_TOTAL + 255) / 256), dim3(256), 0, stream,
                     g1_Whh0, g1_Wih1, g1_Whh1, g2_Whh0, g2_Wih1, g2_Whh1,
                     attn_W, fc_W, wf);

  hipLaunchKernelGGL(gru_attn, dim3(NBLK), dim3(NTHR), 0, stream,
                     received,
                     g1_Wih0, g1_bih0, g1_bhh0, g1_bih1, g1_bhh1,
                     g2_Wih0, g2_bih0, g2_bhh0, g2_bih1, g2_bhh1,
                     fc_b, v_W, out_W, wf, buf, ehb, ws_p);

  hipLaunchKernelGGL(final_combine, dim3((BATCH * TT + 255) / 256), dim3(256), 0, stream,
                     ws_p, out_b, (float*)d_out);
}